// Round 7
// baseline (332.160 us; speedup 1.0000x reference)
//
#include <hip/hip_runtime.h>
#include <cstdint>
#include <cstddef>

typedef __bf16 bf16;
typedef __bf16 bf16x8 __attribute__((ext_vector_type(8)));
typedef __bf16 bf16x4 __attribute__((ext_vector_type(4)));
typedef short  s16x4  __attribute__((ext_vector_type(4)));
typedef float  f32x4  __attribute__((ext_vector_type(4)));

#define MFMA16(a, b, c) __builtin_amdgcn_mfma_f32_16x16x32_bf16((a), (b), (c), 0, 0, 0)

#if __has_builtin(__builtin_amdgcn_mfma_f32_16x16x16bf16_1k)
#define HAVE_K16 1
#else
#define HAVE_K16 0
#endif

// Problem constants
constexpr int Bsz = 4;
constexpr int T   = 2048;
constexpr int Cd  = 1024;
constexpr int Hn  = 16;
constexpr int Mrows = Bsz * T;          // 8192
constexpr int QKV_LD = 3 * Cd;          // 3072

// softmax scale folded into Q at GEMM1 epilogue: 1/sqrt(64) * log2(e)
constexpr float QSCALE = 0.125f * 1.4426950408889634f;

// ---------------------------------------------------------------------------
// fp32 -> bf16 elementwise convert (8 elems / thread)
// ---------------------------------------------------------------------------
__global__ __launch_bounds__(256) void cvt_f32_bf16(const float* __restrict__ in,
                                                    bf16* __restrict__ out, int n) {
    int i = (blockIdx.x * 256 + threadIdx.x) * 8;
    if (i >= n) return;
    float4 a = *(const float4*)(in + i);
    float4 b = *(const float4*)(in + i + 4);
    bf16x8 o;
    o[0] = (bf16)a.x; o[1] = (bf16)a.y; o[2] = (bf16)a.z; o[3] = (bf16)a.w;
    o[4] = (bf16)b.x; o[5] = (bf16)b.y; o[6] = (bf16)b.z; o[7] = (bf16)b.w;
    *(bf16x8*)(out + i) = o;
}

// ---------------------------------------------------------------------------
// W [KDIM][NDIM] fp32 -> Wt [NDIM][KDIM] bf16 (tiled transpose)
// ---------------------------------------------------------------------------
template <int KDIM, int NDIM>
__global__ __launch_bounds__(256) void transpose_cvt(const float* __restrict__ W,
                                                     bf16* __restrict__ Wt) {
    __shared__ float tile[32][33];
    int k0 = blockIdx.y * 32;
    int n0 = blockIdx.x * 32;
    int tx = threadIdx.x;   // 0..31
    int ty = threadIdx.y;   // 0..7
    #pragma unroll
    for (int r = 0; r < 32; r += 8)
        tile[r + ty][tx] = W[(size_t)(k0 + r + ty) * NDIM + n0 + tx];
    __syncthreads();
    #pragma unroll
    for (int r = 0; r < 32; r += 8)
        Wt[(size_t)(n0 + r + ty) * KDIM + k0 + tx] = (bf16)tile[tx][r + ty];
}

// ---------------------------------------------------------------------------
// bf16 MFMA GEMM: out[M][N] = A[M][K] * Bt[N][K]^T + bias  (m97 pattern)
// Columns n < oscale_n get (acc+bias)*oscale in f32 before the bf16 store
// (used to pre-scale Q by 1/sqrt(D)*log2e at zero hot-loop cost).
// ---------------------------------------------------------------------------
template <int N, bool OUT_BF16>
__global__ __launch_bounds__(256) void gemm_bf16(const bf16* __restrict__ A,
                                                 const bf16* __restrict__ Bt,
                                                 const float* __restrict__ bias,
                                                 void* __restrict__ outp,
                                                 float oscale, int oscale_n) {
    constexpr int K = 1024;
    __shared__ __align__(16) bf16 As[128 * 64];
    __shared__ __align__(16) bf16 Bs[128 * 64];

    const int tid  = threadIdx.x;
    const int w    = tid >> 6;
    const int lane = tid & 63;
    const int wm   = w & 1, wn = w >> 1;
    const int quad = lane >> 4, c16 = lane & 15;
    const int m0 = blockIdx.y * 128, n0 = blockIdx.x * 128;

    const int srow = lane >> 3;        // 0..7
    const int scol = (lane & 7) * 8;   // 0..56

    f32x4 acc[4][4] = {};

    for (int kt = 0; kt < K / 64; ++kt) {
        const int kk = kt * 64;
        #pragma unroll
        for (int i = 0; i < 4; ++i) {
            const int arow = 32 * w + 8 * i;
            __builtin_amdgcn_global_load_lds(
                (const __attribute__((address_space(1))) void*)(A + (size_t)(m0 + arow + srow) * K + kk + scol),
                (__attribute__((address_space(3))) void*)(&As[arow * 64]),
                16, 0, 0);
            __builtin_amdgcn_global_load_lds(
                (const __attribute__((address_space(1))) void*)(Bt + (size_t)(n0 + arow + srow) * K + kk + scol),
                (__attribute__((address_space(3))) void*)(&Bs[arow * 64]),
                16, 0, 0);
        }
        __syncthreads();

        #pragma unroll
        for (int ks = 0; ks < 2; ++ks) {
            bf16x8 af[4], bfv[4];
            #pragma unroll
            for (int mb = 0; mb < 4; ++mb)
                af[mb] = *(const bf16x8*)&As[(wm * 64 + mb * 16 + c16) * 64 + ks * 32 + quad * 8];
            #pragma unroll
            for (int nb = 0; nb < 4; ++nb)
                bfv[nb] = *(const bf16x8*)&Bs[(wn * 64 + nb * 16 + c16) * 64 + ks * 32 + quad * 8];
            #pragma unroll
            for (int mb = 0; mb < 4; ++mb)
                #pragma unroll
                for (int nb = 0; nb < 4; ++nb)
                    acc[mb][nb] = MFMA16(af[mb], bfv[nb], acc[mb][nb]);
        }
        __syncthreads();
    }

    #pragma unroll
    for (int nb = 0; nb < 4; ++nb) {
        const int n = n0 + wn * 64 + nb * 16 + c16;
        const float bv = bias[n];
        const float sc = (n < oscale_n) ? oscale : 1.0f;
        #pragma unroll
        for (int mb = 0; mb < 4; ++mb) {
            const int mbase = m0 + wm * 64 + mb * 16 + quad * 4;
            #pragma unroll
            for (int r = 0; r < 4; ++r) {
                float v = (acc[mb][nb][r] + bv) * sc;
                if (OUT_BF16)
                    ((bf16*)outp)[(size_t)(mbase + r) * N + n] = (bf16)v;
                else
                    ((float*)outp)[(size_t)(mbase + r) * N + n] = v;
            }
        }
    }
}

// ---------------------------------------------------------------------------
// Flash-style causal attention, v5: batch-parity CU balance, 4 blocks/CU.
// Grid (16, H, B) = 1024 single-phase blocks; qt = (b&1) ? 15-x : x.
// Round-5/6 counters: dispatcher gives CU i blocks {i, i+256, i+512, i+768}
// (same x, different b) -> pairing qt by batch parity makes each CU's 4
// blocks sum to 68 k-tiles exactly, AND doubles blocks/CU vs v4's 512-grid
// (which capped occupancy at 19.7%). LDS 34 KB * 4 = 139 KB < 160 KB.
// Q arrives pre-scaled by 1/sqrt(D)*log2e (GEMM1 epilogue) -> softmax is
// mask+exp2 only. S^T = K*Q^T keeps P in PV B-fragment registers.
// ---------------------------------------------------------------------------
__global__ __launch_bounds__(256, 4) void attn_fwd(const bf16* __restrict__ qkv,
                                                   bf16* __restrict__ y) {
    __shared__ __align__(16) bf16 Ks2[2][4096];       // [buf][512*key8 + 64*dgrp + 8*k7 + d7]
    __shared__ __align__(16) bf16 Vs[2][64 * 72];     // [buf][d][key], stride 72
#if !HAVE_K16
    __shared__ __align__(16) bf16 Ps[4][32 * 72];     // fallback: [wave][q][key]
#endif

    const int x    = blockIdx.x;                      // 0..15
    const int h    = blockIdx.y;
    const int bb   = blockIdx.z;
    const int qt   = (bb & 1) ? (15 - x) : x;         // batch-parity balance
    const int tid  = threadIdx.x;
    const int w    = tid >> 6;
    const int lane = tid & 63;
    const int quad = lane >> 4, c16 = lane & 15;
    const int q0 = qt * 128;
    const int rowbase = q0 + w * 32;

    const size_t base = (size_t)(bb * T) * QKV_LD;

    const int g = tid >> 5;   // 0..7  : d-group for V staging
    const int p = tid & 31;   // 0..31 : key-pair for V staging

    const int last = 2 * qt + 1;                      // k-tiles 0..last

    // ---- prologue: stage tile 0 into buffer 0 ----
    {
        #pragma unroll
        for (int ii = 0; ii < 2; ++ii) {
            const int i = 2 * w + ii;
            const bf16* gp = qkv + base + (size_t)(8 * i + (lane & 7)) * QKV_LD + Cd + h * 64 + (lane >> 3) * 8;
            __builtin_amdgcn_global_load_lds(
                (const __attribute__((address_space(1))) void*)gp,
                (__attribute__((address_space(3))) void*)(&Ks2[0][i * 512]), 16, 0, 0);
        }
        const bf16* vp = qkv + base + (size_t)(2 * p) * QKV_LD + 2 * Cd + h * 64 + g * 8;
        bf16x8 va = *(const bf16x8*)vp;
        bf16x8 vb = *(const bf16x8*)(vp + QKV_LD);
        #pragma unroll
        for (int j = 0; j < 8; ++j) {
            union { bf16 hh[2]; uint32_t u; } pk;
            pk.hh[0] = va[j]; pk.hh[1] = vb[j];
            *(uint32_t*)&Vs[0][(8 * g + j) * 72 + 2 * p] = pk.u;
        }
    }

    // Q fragments (pre-scaled): lane holds Q[q=c16][d=quad*8+j (+32 for ks=1)]
    bf16x8 qf[2][2];
    #pragma unroll
    for (int mb = 0; mb < 2; ++mb) {
        const bf16* qp = qkv + base + (size_t)(rowbase + 16 * mb + c16) * QKV_LD + h * 64 + quad * 8;
        qf[mb][0] = *(const bf16x8*)qp;
        qf[mb][1] = *(const bf16x8*)(qp + 32);
    }

    f32x4 yacc[2][4] = {};     // HAVE_K16: Y^T[d=quad*4+r][q=c16]
    float lsum[2] = {};

    for (int kt = 0; kt <= last; ++kt) {
        const int cur = kt & 1, nxt = cur ^ 1;
        const int k0 = kt * 64;
        __syncthreads();

        // prefetch tile kt+1
        bf16x8 va, vb;
        const bool more = (kt < last);
        if (more) {
            const int kn = k0 + 64;
            #pragma unroll
            for (int ii = 0; ii < 2; ++ii) {
                const int i = 2 * w + ii;
                const bf16* gp = qkv + base + (size_t)(kn + 8 * i + (lane & 7)) * QKV_LD + Cd + h * 64 + (lane >> 3) * 8;
                __builtin_amdgcn_global_load_lds(
                    (const __attribute__((address_space(1))) void*)gp,
                    (__attribute__((address_space(3))) void*)(&Ks2[nxt][i * 512]), 16, 0, 0);
            }
            const bf16* vp = qkv + base + (size_t)(kn + 2 * p) * QKV_LD + 2 * Cd + h * 64 + g * 8;
            va = *(const bf16x8*)vp;
            vb = *(const bf16x8*)(vp + QKV_LD);
        }

        if (k0 <= rowbase + 31) {   // wave-uniform skip of fully-masked tiles
            // ---- S^T = K Q^T : lane holds S^T[key=16blk+4quad+r][q=c16] ----
            f32x4 s[2][4] = {};
            #pragma unroll
            for (int ks = 0; ks < 2; ++ks)
                #pragma unroll
                for (int blk = 0; blk < 4; ++blk) {
                    const bf16x8 kf = *(const bf16x8*)
                        &Ks2[cur][(2 * blk + (c16 >> 3)) * 512 + (4 * ks + quad) * 64 + (c16 & 7) * 8];
                    #pragma unroll
                    for (int mb = 0; mb < 2; ++mb)
                        s[mb][blk] = MFMA16(kf, qf[mb][ks], s[mb][blk]);
                }

            // ---- softmax: mask + exp2 only (scale pre-folded into Q) ----
#if HAVE_K16
            union B4 { bf16x4 v; s16x4 s; } pb[2][4];
#endif
            #pragma unroll
            for (int mb = 0; mb < 2; ++mb) {
                const int rb = rowbase + 16 * mb;
                const int qglob = rb + c16;
                const bool needMask = (k0 + 63 > rb);   // vs MIN q of block
                #pragma unroll
                for (int blk = 0; blk < 4; ++blk) {
                    #pragma unroll
                    for (int r = 0; r < 4; ++r) {
                        const int key = k0 + blk * 16 + quad * 4 + r;
                        float e = s[mb][blk][r];
                        if (needMask) e = (key > qglob) ? -INFINITY : e;
                        float pv = exp2f(e);
                        lsum[mb] += pv;
#if HAVE_K16
                        pb[mb][blk].v[r] = (bf16)pv;
#else
                        Ps[w][(mb * 16 + c16) * 72 + blk * 16 + quad * 4 + r] = (bf16)pv;
#endif
                    }
                }
            }

#if HAVE_K16
            // ---- Y^T += V^T P^T from registers ----
            #pragma unroll
            for (int blk = 0; blk < 4; ++blk)
                #pragma unroll
                for (int d16 = 0; d16 < 4; ++d16) {
                    union B4u { bf16x4 v; s16x4 s; } vf;
                    vf.v = *(const bf16x4*)&Vs[cur][(d16 * 16 + c16) * 72 + blk * 16 + quad * 4];
                    #pragma unroll
                    for (int mb = 0; mb < 2; ++mb)
                        yacc[mb][d16] = __builtin_amdgcn_mfma_f32_16x16x16bf16_1k(
                            vf.s, pb[mb][blk].s, yacc[mb][d16], 0, 0, 0);
                }
#else
            asm volatile("s_waitcnt lgkmcnt(0)" ::: "memory");
            #pragma unroll
            for (int ks = 0; ks < 2; ++ks) {
                bf16x8 pf0 = *(const bf16x8*)&Ps[w][(0 * 16 + c16) * 72 + ks * 32 + quad * 8];
                bf16x8 pf1 = *(const bf16x8*)&Ps[w][(1 * 16 + c16) * 72 + ks * 32 + quad * 8];
                #pragma unroll
                for (int d16 = 0; d16 < 4; ++d16) {
                    const bf16x8 vfr = *(const bf16x8*)&Vs[cur][(d16 * 16 + c16) * 72 + ks * 32 + quad * 8];
                    yacc[0][d16] = MFMA16(pf0, vfr, yacc[0][d16]);
                    yacc[1][d16] = MFMA16(pf1, vfr, yacc[1][d16]);
                }
            }
#endif
        }

        // write prefetched V (transposed, packed u32 -> conflict-free)
        if (more) {
            #pragma unroll
            for (int j = 0; j < 8; ++j) {
                union { bf16 hh[2]; uint32_t u; } pk;
                pk.hh[0] = va[j]; pk.hh[1] = vb[j];
                *(uint32_t*)&Vs[nxt][(8 * g + j) * 72 + 2 * p] = pk.u;
            }
        }
    }

    // ---- deferred l reduction over quads (lane bits 4,5) ----
    #pragma unroll
    for (int mb = 0; mb < 2; ++mb) {
        lsum[mb] += __shfl_xor(lsum[mb], 16);
        lsum[mb] += __shfl_xor(lsum[mb], 32);
    }

    // ---- epilogue ----
#if HAVE_K16
    #pragma unroll
    for (int mb = 0; mb < 2; ++mb) {
        const float inv = 1.f / lsum[mb];
        const int row = rowbase + 16 * mb + c16;
        bf16* yp = y + (size_t)(bb * T + row) * Cd + h * 64;
        #pragma unroll
        for (int d16 = 0; d16 < 4; ++d16) {
            bf16x4 o;
            #pragma unroll
            for (int r = 0; r < 4; ++r)
                o[r] = (bf16)(yacc[mb][d16][r] * inv);
            *(bf16x4*)(yp + d16 * 16 + quad * 4) = o;
        }
    }
#else
    #pragma unroll
    for (int mb = 0; mb < 2; ++mb)
        #pragma unroll
        for (int r = 0; r < 4; ++r) {
            const float invq = 1.f / __shfl(lsum[mb], quad * 4 + r);
            const int row = rowbase + 16 * mb + quad * 4 + r;
            bf16* yp = y + (size_t)(bb * T + row) * Cd + h * 64;
            #pragma unroll
            for (int d16 = 0; d16 < 4; ++d16)
                yp[d16 * 16 + c16] = (bf16)(yacc[mb][d16][r] * invq);
        }
#endif
}

// ---------------------------------------------------------------------------
extern "C" void kernel_launch(void* const* d_in, const int* in_sizes, int n_in,
                              void* d_out, int out_size, void* d_ws, size_t ws_size,
                              hipStream_t stream) {
    const float* x      = (const float*)d_in[0];
    const float* W_attn = (const float*)d_in[1];
    const float* b_attn = (const float*)d_in[2];
    const float* W_proj = (const float*)d_in[3];
    const float* b_proj = (const float*)d_in[4];
    float* out = (float*)d_out;

    bf16* xb   = (bf16*)d_ws;                               // 8192*1024
    bf16* Wat  = xb  + (size_t)Mrows * Cd;                  // 3072*1024
    bf16* Wpt  = Wat + (size_t)QKV_LD * Cd;                 // 1024*1024
    bf16* qkv  = Wpt + (size_t)Cd * Cd;                     // 8192*3072
    bf16* yb   = qkv + (size_t)Mrows * QKV_LD;              // 8192*1024

    cvt_f32_bf16<<<(Mrows * Cd) / (256 * 8), 256, 0, stream>>>(x, xb, Mrows * Cd);
    transpose_cvt<Cd, QKV_LD><<<dim3(QKV_LD / 32, Cd / 32), dim3(32, 8), 0, stream>>>(W_attn, Wat);
    transpose_cvt<Cd, Cd><<<dim3(Cd / 32, Cd / 32), dim3(32, 8), 0, stream>>>(W_proj, Wpt);

    // Q columns (n < 1024) pre-scaled by 1/sqrt(D)*log2e for the attn exp2
    gemm_bf16<QKV_LD, true><<<dim3(QKV_LD / 128, Mrows / 128), 256, 0, stream>>>(
        xb, Wat, b_attn, qkv, QSCALE, Cd);

    attn_fwd<<<dim3(16, Hn, Bsz), 256, 0, stream>>>(qkv, yb);

    gemm_bf16<Cd, false><<<dim3(Cd / 128, Mrows / 128), 256, 0, stream>>>(
        yb, Wpt, b_proj, out, 1.0f, 0);
}

// Round 8
// 282.413 us; speedup vs baseline: 1.1762x; 1.1762x over previous
//
#include <hip/hip_runtime.h>
#include <cstdint>
#include <cstddef>

typedef __bf16 bf16;
typedef __bf16 bf16x8 __attribute__((ext_vector_type(8)));
typedef __bf16 bf16x4 __attribute__((ext_vector_type(4)));
typedef short  s16x4  __attribute__((ext_vector_type(4)));
typedef float  f32x4  __attribute__((ext_vector_type(4)));

#define MFMA16(a, b, c) __builtin_amdgcn_mfma_f32_16x16x32_bf16((a), (b), (c), 0, 0, 0)

#if __has_builtin(__builtin_amdgcn_mfma_f32_16x16x16bf16_1k)
#define HAVE_K16 1
#else
#define HAVE_K16 0
#endif

// Problem constants
constexpr int Bsz = 4;
constexpr int T   = 2048;
constexpr int Cd  = 1024;
constexpr int Hn  = 16;
constexpr int Mrows = Bsz * T;          // 8192
constexpr int QKV_LD = 3 * Cd;          // 3072

// softmax scale folded into Q at GEMM1 epilogue: 1/sqrt(64) * log2(e)
constexpr float QSCALE = 0.125f * 1.4426950408889634f;

// ---------------------------------------------------------------------------
// fp32 -> bf16 elementwise convert (8 elems / thread)
// ---------------------------------------------------------------------------
__global__ __launch_bounds__(256) void cvt_f32_bf16(const float* __restrict__ in,
                                                    bf16* __restrict__ out, int n) {
    int i = (blockIdx.x * 256 + threadIdx.x) * 8;
    if (i >= n) return;
    float4 a = *(const float4*)(in + i);
    float4 b = *(const float4*)(in + i + 4);
    bf16x8 o;
    o[0] = (bf16)a.x; o[1] = (bf16)a.y; o[2] = (bf16)a.z; o[3] = (bf16)a.w;
    o[4] = (bf16)b.x; o[5] = (bf16)b.y; o[6] = (bf16)b.z; o[7] = (bf16)b.w;
    *(bf16x8*)(out + i) = o;
}

// ---------------------------------------------------------------------------
// W [KDIM][NDIM] fp32 -> Wt [NDIM][KDIM] bf16 (tiled transpose)
// ---------------------------------------------------------------------------
template <int KDIM, int NDIM>
__global__ __launch_bounds__(256) void transpose_cvt(const float* __restrict__ W,
                                                     bf16* __restrict__ Wt) {
    __shared__ float tile[32][33];
    int k0 = blockIdx.y * 32;
    int n0 = blockIdx.x * 32;
    int tx = threadIdx.x;   // 0..31
    int ty = threadIdx.y;   // 0..7
    #pragma unroll
    for (int r = 0; r < 32; r += 8)
        tile[r + ty][tx] = W[(size_t)(k0 + r + ty) * NDIM + n0 + tx];
    __syncthreads();
    #pragma unroll
    for (int r = 0; r < 32; r += 8)
        Wt[(size_t)(n0 + r + ty) * KDIM + k0 + tx] = (bf16)tile[tx][r + ty];
}

// ---------------------------------------------------------------------------
// bf16 MFMA GEMM: out[M][N] = A[M][K] * Bt[N][K]^T + bias  (m97 pattern)
// + granule-XOR LDS swizzle: physical 16B-granule g of row r holds logical
//   g^(r&7). Kills the 16-way same-bank conflicts of stride-128B b128
//   fragment reads (quad-group lanes previously all hit one bank).
// Columns n < oscale_n get (acc+bias)*oscale in f32 before the store.
// ---------------------------------------------------------------------------
template <int N, bool OUT_BF16>
__global__ __launch_bounds__(256) void gemm_bf16(const bf16* __restrict__ A,
                                                 const bf16* __restrict__ Bt,
                                                 const float* __restrict__ bias,
                                                 void* __restrict__ outp,
                                                 float oscale, int oscale_n) {
    constexpr int K = 1024;
    __shared__ __align__(16) bf16 As[128 * 64];
    __shared__ __align__(16) bf16 Bs[128 * 64];

    const int tid  = threadIdx.x;
    const int w    = tid >> 6;
    const int lane = tid & 63;
    const int wm   = w & 1, wn = w >> 1;
    const int quad = lane >> 4, c16 = lane & 15;
    const int m0 = blockIdx.y * 128, n0 = blockIdx.x * 128;

    const int srow = lane >> 3;                      // 0..7
    const int scol = ((lane & 7) ^ srow) * 8;        // swizzled source granule
    const int sw   = c16 & 7;                        // fragment-read swizzle key

    f32x4 acc[4][4] = {};

    for (int kt = 0; kt < K / 64; ++kt) {
        const int kk = kt * 64;
        #pragma unroll
        for (int i = 0; i < 4; ++i) {
            const int arow = 32 * w + 8 * i;
            __builtin_amdgcn_global_load_lds(
                (const __attribute__((address_space(1))) void*)(A + (size_t)(m0 + arow + srow) * K + kk + scol),
                (__attribute__((address_space(3))) void*)(&As[arow * 64]),
                16, 0, 0);
            __builtin_amdgcn_global_load_lds(
                (const __attribute__((address_space(1))) void*)(Bt + (size_t)(n0 + arow + srow) * K + kk + scol),
                (__attribute__((address_space(3))) void*)(&Bs[arow * 64]),
                16, 0, 0);
        }
        __syncthreads();

        #pragma unroll
        for (int ks = 0; ks < 2; ++ks) {
            const int go = ((ks * 4 + quad) ^ sw) * 8;   // swizzled granule offset
            bf16x8 af[4], bfv[4];
            #pragma unroll
            for (int mb = 0; mb < 4; ++mb)
                af[mb] = *(const bf16x8*)&As[(wm * 64 + mb * 16 + c16) * 64 + go];
            #pragma unroll
            for (int nb = 0; nb < 4; ++nb)
                bfv[nb] = *(const bf16x8*)&Bs[(wn * 64 + nb * 16 + c16) * 64 + go];
            #pragma unroll
            for (int mb = 0; mb < 4; ++mb)
                #pragma unroll
                for (int nb = 0; nb < 4; ++nb)
                    acc[mb][nb] = MFMA16(af[mb], bfv[nb], acc[mb][nb]);
        }
        __syncthreads();
    }

    #pragma unroll
    for (int nb = 0; nb < 4; ++nb) {
        const int n = n0 + wn * 64 + nb * 16 + c16;
        const float bv = bias[n];
        const float sc = (n < oscale_n) ? oscale : 1.0f;
        #pragma unroll
        for (int mb = 0; mb < 4; ++mb) {
            const int mbase = m0 + wm * 64 + mb * 16 + quad * 4;
            #pragma unroll
            for (int r = 0; r < 4; ++r) {
                float v = (acc[mb][nb][r] + bv) * sc;
                if (OUT_BF16)
                    ((bf16*)outp)[(size_t)(mbase + r) * N + n] = (bf16)v;
                else
                    ((float*)outp)[(size_t)(mbase + r) * N + n] = v;
            }
        }
    }
}

// ---------------------------------------------------------------------------
// Flash-style causal attention, v6 = round-6 v4 (best measured: 110 us)
// with the in-loop kscale multiply removed (Q pre-scaled by 1/sqrt(D)*log2e
// in GEMM1's epilogue). Two-phase CU-uniform folding: grid (8,H,B)=512
// blocks; block x does q-tile 15-x then x -> every block exactly 34 k-tile
// iterations, all CUs finish together. bounds(256,2): round-7 showed
// bounds(256,4) clamps VGPR to 64 and spills ~10 dwords/thread to scratch
// (+11 MB WRITE_SIZE, +24% dur) -- do not raise.
// ---------------------------------------------------------------------------
__global__ __launch_bounds__(256, 2) void attn_fwd(const bf16* __restrict__ qkv,
                                                   bf16* __restrict__ y) {
    __shared__ __align__(16) bf16 Ks2[2][4096];       // [buf][512*key8 + 64*dgrp + 8*k7 + d7]
    __shared__ __align__(16) bf16 Vs[2][64 * 72];     // [buf][d][key], stride 72
#if !HAVE_K16
    __shared__ __align__(16) bf16 Ps[4][32 * 72];     // fallback: [wave][q][key]
#endif

    const int x    = blockIdx.x;                      // 0..7
    const int h    = blockIdx.y;
    const int bb   = blockIdx.z;
    const int tid  = threadIdx.x;
    const int w    = tid >> 6;
    const int lane = tid & 63;
    const int quad = lane >> 4, c16 = lane & 15;

    const size_t base = (size_t)(bb * T) * QKV_LD;

    const int g = tid >> 5;   // 0..7  : d-group for V staging
    const int p = tid & 31;   // 0..31 : key-pair for V staging

    for (int ph = 0; ph < 2; ++ph) {
        const int qt = ph ? x : (15 - x);             // phase 0: heavy tile
        const int q0 = qt * 128;
        const int rowbase = q0 + w * 32;
        const int last = 2 * qt + 1;                  // k-tiles 0..last

        // protect LDS restage against stragglers of the previous phase
        __syncthreads();

        // ---- prologue: stage tile 0 into buffer 0 ----
        {
            #pragma unroll
            for (int ii = 0; ii < 2; ++ii) {
                const int i = 2 * w + ii;
                const bf16* gp = qkv + base + (size_t)(8 * i + (lane & 7)) * QKV_LD + Cd + h * 64 + (lane >> 3) * 8;
                __builtin_amdgcn_global_load_lds(
                    (const __attribute__((address_space(1))) void*)gp,
                    (__attribute__((address_space(3))) void*)(&Ks2[0][i * 512]), 16, 0, 0);
            }
            const bf16* vp = qkv + base + (size_t)(2 * p) * QKV_LD + 2 * Cd + h * 64 + g * 8;
            bf16x8 va = *(const bf16x8*)vp;
            bf16x8 vb = *(const bf16x8*)(vp + QKV_LD);
            #pragma unroll
            for (int j = 0; j < 8; ++j) {
                union { bf16 hh[2]; uint32_t u; } pk;
                pk.hh[0] = va[j]; pk.hh[1] = vb[j];
                *(uint32_t*)&Vs[0][(8 * g + j) * 72 + 2 * p] = pk.u;
            }
        }

        // Q fragments (pre-scaled): lane holds Q[q=c16][d=quad*8+j (+32 for ks=1)]
        bf16x8 qf[2][2];
        #pragma unroll
        for (int mb = 0; mb < 2; ++mb) {
            const bf16* qp = qkv + base + (size_t)(rowbase + 16 * mb + c16) * QKV_LD + h * 64 + quad * 8;
            qf[mb][0] = *(const bf16x8*)qp;
            qf[mb][1] = *(const bf16x8*)(qp + 32);
        }

        f32x4 yacc[2][4] = {};     // HAVE_K16: Y^T[d=quad*4+r][q=c16]
        float lsum[2] = {};

        for (int kt = 0; kt <= last; ++kt) {
            const int cur = kt & 1, nxt = cur ^ 1;
            const int k0 = kt * 64;
            __syncthreads();

            // prefetch tile kt+1
            bf16x8 va, vb;
            const bool more = (kt < last);
            if (more) {
                const int kn = k0 + 64;
                #pragma unroll
                for (int ii = 0; ii < 2; ++ii) {
                    const int i = 2 * w + ii;
                    const bf16* gp = qkv + base + (size_t)(kn + 8 * i + (lane & 7)) * QKV_LD + Cd + h * 64 + (lane >> 3) * 8;
                    __builtin_amdgcn_global_load_lds(
                        (const __attribute__((address_space(1))) void*)gp,
                        (__attribute__((address_space(3))) void*)(&Ks2[nxt][i * 512]), 16, 0, 0);
                }
                const bf16* vp = qkv + base + (size_t)(kn + 2 * p) * QKV_LD + 2 * Cd + h * 64 + g * 8;
                va = *(const bf16x8*)vp;
                vb = *(const bf16x8*)(vp + QKV_LD);
            }

            if (k0 <= rowbase + 31) {   // wave-uniform skip of fully-masked tiles
                // ---- S^T = K Q^T : lane holds S^T[key=16blk+4quad+r][q=c16] ----
                f32x4 s[2][4] = {};
                #pragma unroll
                for (int ks = 0; ks < 2; ++ks)
                    #pragma unroll
                    for (int blk = 0; blk < 4; ++blk) {
                        const bf16x8 kf = *(const bf16x8*)
                            &Ks2[cur][(2 * blk + (c16 >> 3)) * 512 + (4 * ks + quad) * 64 + (c16 & 7) * 8];
                        #pragma unroll
                        for (int mb = 0; mb < 2; ++mb)
                            s[mb][blk] = MFMA16(kf, qf[mb][ks], s[mb][blk]);
                    }

                // ---- softmax: mask + exp2 only (scale pre-folded into Q) ----
#if HAVE_K16
                union B4 { bf16x4 v; s16x4 s; } pb[2][4];
#endif
                #pragma unroll
                for (int mb = 0; mb < 2; ++mb) {
                    const int rb = rowbase + 16 * mb;
                    const int qglob = rb + c16;
                    const bool needMask = (k0 + 63 > rb);   // vs MIN q of block
                    #pragma unroll
                    for (int blk = 0; blk < 4; ++blk) {
                        #pragma unroll
                        for (int r = 0; r < 4; ++r) {
                            const int key = k0 + blk * 16 + quad * 4 + r;
                            float e = s[mb][blk][r];
                            if (needMask) e = (key > qglob) ? -INFINITY : e;
                            float pv = exp2f(e);
                            lsum[mb] += pv;
#if HAVE_K16
                            pb[mb][blk].v[r] = (bf16)pv;
#else
                            Ps[w][(mb * 16 + c16) * 72 + blk * 16 + quad * 4 + r] = (bf16)pv;
#endif
                        }
                    }
                }

#if HAVE_K16
                // ---- Y^T += V^T P^T from registers ----
                #pragma unroll
                for (int blk = 0; blk < 4; ++blk)
                    #pragma unroll
                    for (int d16 = 0; d16 < 4; ++d16) {
                        union B4u { bf16x4 v; s16x4 s; } vf;
                        vf.v = *(const bf16x4*)&Vs[cur][(d16 * 16 + c16) * 72 + blk * 16 + quad * 4];
                        #pragma unroll
                        for (int mb = 0; mb < 2; ++mb)
                            yacc[mb][d16] = __builtin_amdgcn_mfma_f32_16x16x16bf16_1k(
                                vf.s, pb[mb][blk].s, yacc[mb][d16], 0, 0, 0);
                    }
#else
                asm volatile("s_waitcnt lgkmcnt(0)" ::: "memory");
                #pragma unroll
                for (int ks = 0; ks < 2; ++ks) {
                    bf16x8 pf0 = *(const bf16x8*)&Ps[w][(0 * 16 + c16) * 72 + ks * 32 + quad * 8];
                    bf16x8 pf1 = *(const bf16x8*)&Ps[w][(1 * 16 + c16) * 72 + ks * 32 + quad * 8];
                    #pragma unroll
                    for (int d16 = 0; d16 < 4; ++d16) {
                        const bf16x8 vfr = *(const bf16x8*)&Vs[cur][(d16 * 16 + c16) * 72 + ks * 32 + quad * 8];
                        yacc[0][d16] = MFMA16(pf0, vfr, yacc[0][d16]);
                        yacc[1][d16] = MFMA16(pf1, vfr, yacc[1][d16]);
                    }
                }
#endif
            }

            // write prefetched V (transposed, packed u32 -> conflict-free)
            if (more) {
                #pragma unroll
                for (int j = 0; j < 8; ++j) {
                    union { bf16 hh[2]; uint32_t u; } pk;
                    pk.hh[0] = va[j]; pk.hh[1] = vb[j];
                    *(uint32_t*)&Vs[nxt][(8 * g + j) * 72 + 2 * p] = pk.u;
                }
            }
        }

        // ---- deferred l reduction over quads (lane bits 4,5) ----
        #pragma unroll
        for (int mb = 0; mb < 2; ++mb) {
            lsum[mb] += __shfl_xor(lsum[mb], 16);
            lsum[mb] += __shfl_xor(lsum[mb], 32);
        }

        // ---- epilogue for this q-tile ----
#if HAVE_K16
        #pragma unroll
        for (int mb = 0; mb < 2; ++mb) {
            const float inv = 1.f / lsum[mb];
            const int row = rowbase + 16 * mb + c16;
            bf16* yp = y + (size_t)(bb * T + row) * Cd + h * 64;
            #pragma unroll
            for (int d16 = 0; d16 < 4; ++d16) {
                bf16x4 o;
                #pragma unroll
                for (int r = 0; r < 4; ++r)
                    o[r] = (bf16)(yacc[mb][d16][r] * inv);
                *(bf16x4*)(yp + d16 * 16 + quad * 4) = o;
            }
        }
#else
        #pragma unroll
        for (int mb = 0; mb < 2; ++mb)
            #pragma unroll
            for (int r = 0; r < 4; ++r) {
                const float invq = 1.f / __shfl(lsum[mb], quad * 4 + r);
                const int row = rowbase + 16 * mb + quad * 4 + r;
                bf16* yp = y + (size_t)(bb * T + row) * Cd + h * 64;
                #pragma unroll
                for (int d16 = 0; d16 < 4; ++d16)
                    yp[d16 * 16 + c16] = (bf16)(yacc[mb][d16][r] * invq);
            }
#endif
    }
}

// ---------------------------------------------------------------------------
extern "C" void kernel_launch(void* const* d_in, const int* in_sizes, int n_in,
                              void* d_out, int out_size, void* d_ws, size_t ws_size,
                              hipStream_t stream) {
    const float* x      = (const float*)d_in[0];
    const float* W_attn = (const float*)d_in[1];
    const float* b_attn = (const float*)d_in[2];
    const float* W_proj = (const float*)d_in[3];
    const float* b_proj = (const float*)d_in[4];
    float* out = (float*)d_out;

    bf16* xb   = (bf16*)d_ws;                               // 8192*1024
    bf16* Wat  = xb  + (size_t)Mrows * Cd;                  // 3072*1024
    bf16* Wpt  = Wat + (size_t)QKV_LD * Cd;                 // 1024*1024
    bf16* qkv  = Wpt + (size_t)Cd * Cd;                     // 8192*3072
    bf16* yb   = qkv + (size_t)Mrows * QKV_LD;              // 8192*1024

    cvt_f32_bf16<<<(Mrows * Cd) / (256 * 8), 256, 0, stream>>>(x, xb, Mrows * Cd);
    transpose_cvt<Cd, QKV_LD><<<dim3(QKV_LD / 32, Cd / 32), dim3(32, 8), 0, stream>>>(W_attn, Wat);
    transpose_cvt<Cd, Cd><<<dim3(Cd / 32, Cd / 32), dim3(32, 8), 0, stream>>>(W_proj, Wpt);

    // Q columns (n < 1024) pre-scaled by 1/sqrt(D)*log2e for the attn exp2
    gemm_bf16<QKV_LD, true><<<dim3(QKV_LD / 128, Mrows / 128), 256, 0, stream>>>(
        xb, Wat, b_attn, qkv, QSCALE, Cd);

    attn_fwd<<<dim3(8, Hn, Bsz), 256, 0, stream>>>(qkv, yb);

    gemm_bf16<Cd, false><<<dim3(Cd / 128, Mrows / 128), 256, 0, stream>>>(
        yb, Wpt, b_proj, out, 1.0f, 0);
}

// Round 9
// 277.802 us; speedup vs baseline: 1.1957x; 1.0166x over previous
//
#include <hip/hip_runtime.h>
#include <cstdint>
#include <cstddef>

typedef __bf16 bf16;
typedef __bf16 bf16x8 __attribute__((ext_vector_type(8)));
typedef __bf16 bf16x4 __attribute__((ext_vector_type(4)));
typedef short  s16x4  __attribute__((ext_vector_type(4)));
typedef float  f32x4  __attribute__((ext_vector_type(4)));

#define MFMA16(a, b, c) __builtin_amdgcn_mfma_f32_16x16x32_bf16((a), (b), (c), 0, 0, 0)

#if __has_builtin(__builtin_amdgcn_mfma_f32_16x16x16bf16_1k)
#define HAVE_K16 1
#else
#define HAVE_K16 0
#endif

#if __has_builtin(__builtin_amdgcn_exp2f)
#define EXP2(x) __builtin_amdgcn_exp2f(x)
#else
#define EXP2(x) exp2f(x)
#endif

// Problem constants
constexpr int Bsz = 4;
constexpr int T   = 2048;
constexpr int Cd  = 1024;
constexpr int Hn  = 16;
constexpr int Mrows = Bsz * T;          // 8192
constexpr int QKV_LD = 3 * Cd;          // 3072

// softmax scale folded into Q at GEMM1 epilogue: 1/sqrt(64) * log2(e)
constexpr float QSCALE = 0.125f * 1.4426950408889634f;

// ---------------------------------------------------------------------------
// fp32 -> bf16 elementwise convert (8 elems / thread)
// ---------------------------------------------------------------------------
__global__ __launch_bounds__(256) void cvt_f32_bf16(const float* __restrict__ in,
                                                    bf16* __restrict__ out, int n) {
    int i = (blockIdx.x * 256 + threadIdx.x) * 8;
    if (i >= n) return;
    float4 a = *(const float4*)(in + i);
    float4 b = *(const float4*)(in + i + 4);
    bf16x8 o;
    o[0] = (bf16)a.x; o[1] = (bf16)a.y; o[2] = (bf16)a.z; o[3] = (bf16)a.w;
    o[4] = (bf16)b.x; o[5] = (bf16)b.y; o[6] = (bf16)b.z; o[7] = (bf16)b.w;
    *(bf16x8*)(out + i) = o;
}

// ---------------------------------------------------------------------------
// W [KDIM][NDIM] fp32 -> Wt [NDIM][KDIM] bf16 (tiled transpose)
// ---------------------------------------------------------------------------
template <int KDIM, int NDIM>
__global__ __launch_bounds__(256) void transpose_cvt(const float* __restrict__ W,
                                                     bf16* __restrict__ Wt) {
    __shared__ float tile[32][33];
    int k0 = blockIdx.y * 32;
    int n0 = blockIdx.x * 32;
    int tx = threadIdx.x;   // 0..31
    int ty = threadIdx.y;   // 0..7
    #pragma unroll
    for (int r = 0; r < 32; r += 8)
        tile[r + ty][tx] = W[(size_t)(k0 + r + ty) * NDIM + n0 + tx];
    __syncthreads();
    #pragma unroll
    for (int r = 0; r < 32; r += 8)
        Wt[(size_t)(n0 + r + ty) * KDIM + k0 + tx] = (bf16)tile[tx][r + ty];
}

// ---------------------------------------------------------------------------
// bf16 MFMA GEMM: out[M][N] = A[M][K] * Bt[N][K]^T + bias  (m97 pattern)
// + granule-XOR LDS swizzle (round-8 win: kills 16-way b128 read conflicts).
// Columns n < oscale_n get (acc+bias)*oscale in f32 before the store.
// ---------------------------------------------------------------------------
template <int N, bool OUT_BF16>
__global__ __launch_bounds__(256) void gemm_bf16(const bf16* __restrict__ A,
                                                 const bf16* __restrict__ Bt,
                                                 const float* __restrict__ bias,
                                                 void* __restrict__ outp,
                                                 float oscale, int oscale_n) {
    constexpr int K = 1024;
    __shared__ __align__(16) bf16 As[128 * 64];
    __shared__ __align__(16) bf16 Bs[128 * 64];

    const int tid  = threadIdx.x;
    const int w    = tid >> 6;
    const int lane = tid & 63;
    const int wm   = w & 1, wn = w >> 1;
    const int quad = lane >> 4, c16 = lane & 15;
    const int m0 = blockIdx.y * 128, n0 = blockIdx.x * 128;

    const int srow = lane >> 3;                      // 0..7
    const int scol = ((lane & 7) ^ srow) * 8;        // swizzled source granule
    const int sw   = c16 & 7;                        // fragment-read swizzle key

    f32x4 acc[4][4] = {};

    for (int kt = 0; kt < K / 64; ++kt) {
        const int kk = kt * 64;
        #pragma unroll
        for (int i = 0; i < 4; ++i) {
            const int arow = 32 * w + 8 * i;
            __builtin_amdgcn_global_load_lds(
                (const __attribute__((address_space(1))) void*)(A + (size_t)(m0 + arow + srow) * K + kk + scol),
                (__attribute__((address_space(3))) void*)(&As[arow * 64]),
                16, 0, 0);
            __builtin_amdgcn_global_load_lds(
                (const __attribute__((address_space(1))) void*)(Bt + (size_t)(n0 + arow + srow) * K + kk + scol),
                (__attribute__((address_space(3))) void*)(&Bs[arow * 64]),
                16, 0, 0);
        }
        __syncthreads();

        #pragma unroll
        for (int ks = 0; ks < 2; ++ks) {
            const int go = ((ks * 4 + quad) ^ sw) * 8;   // swizzled granule offset
            bf16x8 af[4], bfv[4];
            #pragma unroll
            for (int mb = 0; mb < 4; ++mb)
                af[mb] = *(const bf16x8*)&As[(wm * 64 + mb * 16 + c16) * 64 + go];
            #pragma unroll
            for (int nb = 0; nb < 4; ++nb)
                bfv[nb] = *(const bf16x8*)&Bs[(wn * 64 + nb * 16 + c16) * 64 + go];
            #pragma unroll
            for (int mb = 0; mb < 4; ++mb)
                #pragma unroll
                for (int nb = 0; nb < 4; ++nb)
                    acc[mb][nb] = MFMA16(af[mb], bfv[nb], acc[mb][nb]);
        }
        __syncthreads();
    }

    #pragma unroll
    for (int nb = 0; nb < 4; ++nb) {
        const int n = n0 + wn * 64 + nb * 16 + c16;
        const float bv = bias[n];
        const float sc = (n < oscale_n) ? oscale : 1.0f;
        #pragma unroll
        for (int mb = 0; mb < 4; ++mb) {
            const int mbase = m0 + wm * 64 + mb * 16 + quad * 4;
            #pragma unroll
            for (int r = 0; r < 4; ++r) {
                float v = (acc[mb][nb][r] + bv) * sc;
                if (OUT_BF16)
                    ((bf16*)outp)[(size_t)(mbase + r) * N + n] = (bf16)v;
                else
                    ((float*)outp)[(size_t)(mbase + r) * N + n] = v;
            }
        }
    }
}

// ---------------------------------------------------------------------------
// Flash-style causal attention, v7: split-K (flash-decoding) for 4 blocks/CU.
// Round-8 counters: SIMD issue occupancy ~16% at 2 waves/SIMD -> pure
// latency-bound; q/(b,h) parallelism exhausted. Since softmax has no
// max-subtraction, partials are ADDITIVE: two blocks split each q-tile's
// key range (s=0: kt 0..qt; s=1: kt qt+1..2qt+1 -- each qt+1 iters).
// Two-phase fold (qt=15-xq then xq) keeps every block at EXACTLY 17 iters.
// Grid (32? no) (16*2? ) -> (2*16/2...) (x in [0,16): xq=x>>1, s=x&1),
// 1024 blocks -> 4 blocks/CU (VGPR 80<=128, LDS 139KB<=160KB).
// Blocks write UNNORMALIZED bf16 y-partials + f32 l-partials; attn_combine
// does (y0+y1)/(l0+l1). bounds(256,2): round 7 proved (256,4) spills.
// ---------------------------------------------------------------------------
__global__ __launch_bounds__(256, 2) void attn_fwd(const bf16* __restrict__ qkv,
                                                   bf16* __restrict__ yp0,
                                                   bf16* __restrict__ yp1,
                                                   float* __restrict__ lp) {
    __shared__ __align__(16) bf16 Ks2[2][4096];       // [buf][512*key8 + 64*dgrp + 8*k7 + d7]
    __shared__ __align__(16) bf16 Vs[2][64 * 72];     // [buf][d][key], stride 72
#if !HAVE_K16
    __shared__ __align__(16) bf16 Ps[4][32 * 72];     // fallback: [wave][q][key]
#endif

    const int x    = blockIdx.x;                      // 0..15
    const int xq   = x >> 1;                          // 0..7
    const int sgl  = x & 1;                           // key-range half
    const int h    = blockIdx.y;
    const int bb   = blockIdx.z;
    const int tid  = threadIdx.x;
    const int w    = tid >> 6;
    const int lane = tid & 63;
    const int quad = lane >> 4, c16 = lane & 15;

    const size_t base = (size_t)(bb * T) * QKV_LD;

    const int g = tid >> 5;   // 0..7  : d-group for V staging
    const int p = tid & 31;   // 0..31 : key-pair for V staging

    bf16* __restrict__ ydst = sgl ? yp1 : yp0;
    float* __restrict__ ldst = lp + (size_t)sgl * Mrows * Hn;

    for (int ph = 0; ph < 2; ++ph) {
        const int qt = ph ? xq : (15 - xq);           // phase 0: heavy tile
        const int q0 = qt * 128;
        const int rowbase = q0 + w * 32;
        const int start = sgl ? (qt + 1) : 0;         // first k-tile of my half
        const int nkt = qt + 1;                       // iterations in my half

        // protect LDS restage against stragglers of the previous phase
        __syncthreads();

        // ---- prologue: stage tile (start) into buffer 0 ----
        {
            const int kb = start * 64;
            #pragma unroll
            for (int ii = 0; ii < 2; ++ii) {
                const int i = 2 * w + ii;
                const bf16* gp = qkv + base + (size_t)(kb + 8 * i + (lane & 7)) * QKV_LD + Cd + h * 64 + (lane >> 3) * 8;
                __builtin_amdgcn_global_load_lds(
                    (const __attribute__((address_space(1))) void*)gp,
                    (__attribute__((address_space(3))) void*)(&Ks2[0][i * 512]), 16, 0, 0);
            }
            const bf16* vp = qkv + base + (size_t)(kb + 2 * p) * QKV_LD + 2 * Cd + h * 64 + g * 8;
            bf16x8 va = *(const bf16x8*)vp;
            bf16x8 vb = *(const bf16x8*)(vp + QKV_LD);
            #pragma unroll
            for (int j = 0; j < 8; ++j) {
                union { bf16 hh[2]; uint32_t u; } pk;
                pk.hh[0] = va[j]; pk.hh[1] = vb[j];
                *(uint32_t*)&Vs[0][(8 * g + j) * 72 + 2 * p] = pk.u;
            }
        }

        // Q fragments (pre-scaled): lane holds Q[q=c16][d=quad*8+j (+32 for ks=1)]
        bf16x8 qf[2][2];
        #pragma unroll
        for (int mb = 0; mb < 2; ++mb) {
            const bf16* qp = qkv + base + (size_t)(rowbase + 16 * mb + c16) * QKV_LD + h * 64 + quad * 8;
            qf[mb][0] = *(const bf16x8*)qp;
            qf[mb][1] = *(const bf16x8*)(qp + 32);
        }

        f32x4 yacc[2][4] = {};     // HAVE_K16: Y^T[d=quad*4+r][q=c16]
        float lsum[2] = {};

        for (int j = 0; j < nkt; ++j) {
            const int cur = j & 1, nxt = cur ^ 1;
            const int k0 = (start + j) * 64;
            __syncthreads();

            // prefetch tile start+j+1
            bf16x8 va, vb;
            const bool more = (j + 1 < nkt);
            if (more) {
                const int kn = k0 + 64;
                #pragma unroll
                for (int ii = 0; ii < 2; ++ii) {
                    const int i = 2 * w + ii;
                    const bf16* gp = qkv + base + (size_t)(kn + 8 * i + (lane & 7)) * QKV_LD + Cd + h * 64 + (lane >> 3) * 8;
                    __builtin_amdgcn_global_load_lds(
                        (const __attribute__((address_space(1))) void*)gp,
                        (__attribute__((address_space(3))) void*)(&Ks2[nxt][i * 512]), 16, 0, 0);
                }
                const bf16* vp = qkv + base + (size_t)(kn + 2 * p) * QKV_LD + 2 * Cd + h * 64 + g * 8;
                va = *(const bf16x8*)vp;
                vb = *(const bf16x8*)(vp + QKV_LD);
            }

            if (k0 <= rowbase + 31) {   // wave-uniform skip of fully-masked tiles
                // ---- S^T = K Q^T : lane holds S^T[key=16blk+4quad+r][q=c16] ----
                f32x4 s[2][4] = {};
                #pragma unroll
                for (int ks = 0; ks < 2; ++ks)
                    #pragma unroll
                    for (int blk = 0; blk < 4; ++blk) {
                        const bf16x8 kf = *(const bf16x8*)
                            &Ks2[cur][(2 * blk + (c16 >> 3)) * 512 + (4 * ks + quad) * 64 + (c16 & 7) * 8];
                        #pragma unroll
                        for (int mb = 0; mb < 2; ++mb)
                            s[mb][blk] = MFMA16(kf, qf[mb][ks], s[mb][blk]);
                    }

                // ---- softmax: mask + exp2 only (scale pre-folded into Q) ----
#if HAVE_K16
                union B4 { bf16x4 v; s16x4 s; } pb[2][4];
#endif
                #pragma unroll
                for (int mb = 0; mb < 2; ++mb) {
                    const int rb = rowbase + 16 * mb;
                    const int qglob = rb + c16;
                    const bool needMask = (k0 + 63 > rb);   // vs MIN q of block
                    #pragma unroll
                    for (int blk = 0; blk < 4; ++blk) {
                        #pragma unroll
                        for (int r = 0; r < 4; ++r) {
                            const int key = k0 + blk * 16 + quad * 4 + r;
                            float e = s[mb][blk][r];
                            if (needMask) e = (key > qglob) ? -INFINITY : e;
                            float pv = EXP2(e);
                            lsum[mb] += pv;
#if HAVE_K16
                            pb[mb][blk].v[r] = (bf16)pv;
#else
                            Ps[w][(mb * 16 + c16) * 72 + blk * 16 + quad * 4 + r] = (bf16)pv;
#endif
                        }
                    }
                }

#if HAVE_K16
                // ---- Y^T += V^T P^T from registers ----
                #pragma unroll
                for (int blk = 0; blk < 4; ++blk)
                    #pragma unroll
                    for (int d16 = 0; d16 < 4; ++d16) {
                        union B4u { bf16x4 v; s16x4 s; } vf;
                        vf.v = *(const bf16x4*)&Vs[cur][(d16 * 16 + c16) * 72 + blk * 16 + quad * 4];
                        #pragma unroll
                        for (int mb = 0; mb < 2; ++mb)
                            yacc[mb][d16] = __builtin_amdgcn_mfma_f32_16x16x16bf16_1k(
                                vf.s, pb[mb][blk].s, yacc[mb][d16], 0, 0, 0);
                    }
#else
                asm volatile("s_waitcnt lgkmcnt(0)" ::: "memory");
                #pragma unroll
                for (int ks = 0; ks < 2; ++ks) {
                    bf16x8 pf0 = *(const bf16x8*)&Ps[w][(0 * 16 + c16) * 72 + ks * 32 + quad * 8];
                    bf16x8 pf1 = *(const bf16x8*)&Ps[w][(1 * 16 + c16) * 72 + ks * 32 + quad * 8];
                    #pragma unroll
                    for (int d16 = 0; d16 < 4; ++d16) {
                        const bf16x8 vfr = *(const bf16x8*)&Vs[cur][(d16 * 16 + c16) * 72 + ks * 32 + quad * 8];
                        yacc[0][d16] = MFMA16(pf0, vfr, yacc[0][d16]);
                        yacc[1][d16] = MFMA16(pf1, vfr, yacc[1][d16]);
                    }
                }
#endif
            }

            // write prefetched V (transposed, packed u32 -> conflict-free)
            if (more) {
                #pragma unroll
                for (int j2 = 0; j2 < 8; ++j2) {
                    union { bf16 hh[2]; uint32_t u; } pk;
                    pk.hh[0] = va[j2]; pk.hh[1] = vb[j2];
                    *(uint32_t*)&Vs[nxt][(8 * g + j2) * 72 + 2 * p] = pk.u;
                }
            }
        }

        // ---- deferred l reduction over quads (lane bits 4,5) ----
        #pragma unroll
        for (int mb = 0; mb < 2; ++mb) {
            lsum[mb] += __shfl_xor(lsum[mb], 16);
            lsum[mb] += __shfl_xor(lsum[mb], 32);
        }

        // ---- epilogue: UNNORMALIZED partial + l ----
#if HAVE_K16
        #pragma unroll
        for (int mb = 0; mb < 2; ++mb) {
            const int row = rowbase + 16 * mb + c16;
            bf16* yw = ydst + (size_t)(bb * T + row) * Cd + h * 64;
            #pragma unroll
            for (int d16 = 0; d16 < 4; ++d16) {
                bf16x4 o;
                #pragma unroll
                for (int r = 0; r < 4; ++r)
                    o[r] = (bf16)(yacc[mb][d16][r]);
                *(bf16x4*)(yw + d16 * 16 + quad * 4) = o;
            }
            if (quad == 0)
                ldst[(size_t)(bb * T + row) * Hn + h] = lsum[mb];
        }
#else
        #pragma unroll
        for (int mb = 0; mb < 2; ++mb)
            #pragma unroll
            for (int r = 0; r < 4; ++r) {
                const float lsv = __shfl(lsum[mb], quad * 4 + r);
                const int row = rowbase + 16 * mb + quad * 4 + r;
                bf16* yw = ydst + (size_t)(bb * T + row) * Cd + h * 64;
                #pragma unroll
                for (int d16 = 0; d16 < 4; ++d16)
                    yw[d16 * 16 + c16] = (bf16)(yacc[mb][d16][r]);
                if (c16 == 0)
                    ldst[(size_t)(bb * T + row) * Hn + h] = lsv;
            }
#endif
    }
}

// ---------------------------------------------------------------------------
// Combine split-K partials: y = (y0 + y1) / (l0 + l1). 8 elems/thread,
// all 8 within one head (64 % 8 == 0). In-place safe (y aliases yp0).
// ---------------------------------------------------------------------------
__global__ __launch_bounds__(256) void attn_combine(const bf16* __restrict__ yp0,
                                                    const bf16* __restrict__ yp1,
                                                    const float* __restrict__ lp,
                                                    bf16* __restrict__ y) {
    int i = (blockIdx.x * 256 + threadIdx.x) * 8;
    int row = i >> 10;          // / Cd
    int hh  = (i & 1023) >> 6;  // head
    float l = lp[(size_t)row * Hn + hh] + lp[(size_t)Mrows * Hn + (size_t)row * Hn + hh];
    float inv = 1.f / l;
    bf16x8 a = *(const bf16x8*)(yp0 + i);
    bf16x8 b = *(const bf16x8*)(yp1 + i);
    bf16x8 o;
    #pragma unroll
    for (int j = 0; j < 8; ++j)
        o[j] = (bf16)(((float)a[j] + (float)b[j]) * inv);
    *(bf16x8*)(y + i) = o;
}

// ---------------------------------------------------------------------------
extern "C" void kernel_launch(void* const* d_in, const int* in_sizes, int n_in,
                              void* d_out, int out_size, void* d_ws, size_t ws_size,
                              hipStream_t stream) {
    const float* x      = (const float*)d_in[0];
    const float* W_attn = (const float*)d_in[1];
    const float* b_attn = (const float*)d_in[2];
    const float* W_proj = (const float*)d_in[3];
    const float* b_proj = (const float*)d_in[4];
    float* out = (float*)d_out;

    bf16* xb   = (bf16*)d_ws;                               // 16.8 MB
    bf16* Wat  = xb  + (size_t)Mrows * Cd;                  // 6.3 MB
    bf16* Wpt  = Wat + (size_t)QKV_LD * Cd;                 // 2.1 MB
    bf16* qkv  = Wpt + (size_t)Cd * Cd;                     // 50.3 MB
    bf16* yb   = qkv + (size_t)Mrows * QKV_LD;              // 16.8 MB (yp0 + combined)
    bf16* yp1  = yb  + (size_t)Mrows * Cd;                  // 16.8 MB
    float* lp  = (float*)(yp1 + (size_t)Mrows * Cd);        // 1.05 MB (2 x M x H)

    cvt_f32_bf16<<<(Mrows * Cd) / (256 * 8), 256, 0, stream>>>(x, xb, Mrows * Cd);
    transpose_cvt<Cd, QKV_LD><<<dim3(QKV_LD / 32, Cd / 32), dim3(32, 8), 0, stream>>>(W_attn, Wat);
    transpose_cvt<Cd, Cd><<<dim3(Cd / 32, Cd / 32), dim3(32, 8), 0, stream>>>(W_proj, Wpt);

    // Q columns (n < 1024) pre-scaled by 1/sqrt(D)*log2e for the attn exp2
    gemm_bf16<QKV_LD, true><<<dim3(QKV_LD / 128, Mrows / 128), 256, 0, stream>>>(
        xb, Wat, b_attn, qkv, QSCALE, Cd);

    attn_fwd<<<dim3(16, Hn, Bsz), 256, 0, stream>>>(qkv, yb, yp1, lp);
    attn_combine<<<(Mrows * Cd) / (256 * 8), 256, 0, stream>>>(yb, yp1, lp, yb);

    gemm_bf16<Cd, false><<<dim3(Cd / 128, Mrows / 128), 256, 0, stream>>>(
        yb, Wpt, b_proj, out, 1.0f, 0);
}

// Round 10
// 277.147 us; speedup vs baseline: 1.1985x; 1.0024x over previous
//
#include <hip/hip_runtime.h>
#include <cstdint>
#include <cstddef>

typedef __bf16 bf16;
typedef __bf16 bf16x8 __attribute__((ext_vector_type(8)));
typedef __bf16 bf16x4 __attribute__((ext_vector_type(4)));
typedef short  s16x4  __attribute__((ext_vector_type(4)));
typedef float  f32x4  __attribute__((ext_vector_type(4)));

#define MFMA16(a, b, c) __builtin_amdgcn_mfma_f32_16x16x32_bf16((a), (b), (c), 0, 0, 0)

#if __has_builtin(__builtin_amdgcn_mfma_f32_16x16x16bf16_1k)
#define HAVE_K16 1
#else
#define HAVE_K16 0
#endif

#if __has_builtin(__builtin_amdgcn_exp2f)
#define EXP2(x) __builtin_amdgcn_exp2f(x)
#else
#define EXP2(x) exp2f(x)
#endif

// Problem constants
constexpr int Bsz = 4;
constexpr int T   = 2048;
constexpr int Cd  = 1024;
constexpr int Hn  = 16;
constexpr int Mrows = Bsz * T;          // 8192
constexpr int QKV_LD = 3 * Cd;          // 3072

// softmax scale folded into Q at GEMM1 epilogue: 1/sqrt(64) * log2(e)
constexpr float QSCALE = 0.125f * 1.4426950408889634f;

// ---------------------------------------------------------------------------
// fp32 -> bf16 elementwise convert (8 elems / thread)
// ---------------------------------------------------------------------------
__global__ __launch_bounds__(256) void cvt_f32_bf16(const float* __restrict__ in,
                                                    bf16* __restrict__ out, int n) {
    int i = (blockIdx.x * 256 + threadIdx.x) * 8;
    if (i >= n) return;
    float4 a = *(const float4*)(in + i);
    float4 b = *(const float4*)(in + i + 4);
    bf16x8 o;
    o[0] = (bf16)a.x; o[1] = (bf16)a.y; o[2] = (bf16)a.z; o[3] = (bf16)a.w;
    o[4] = (bf16)b.x; o[5] = (bf16)b.y; o[6] = (bf16)b.z; o[7] = (bf16)b.w;
    *(bf16x8*)(out + i) = o;
}

// ---------------------------------------------------------------------------
// W [KDIM][NDIM] fp32 -> Wt [NDIM][KDIM] bf16 (tiled transpose)
// ---------------------------------------------------------------------------
template <int KDIM, int NDIM>
__global__ __launch_bounds__(256) void transpose_cvt(const float* __restrict__ W,
                                                     bf16* __restrict__ Wt) {
    __shared__ float tile[32][33];
    int k0 = blockIdx.y * 32;
    int n0 = blockIdx.x * 32;
    int tx = threadIdx.x;   // 0..31
    int ty = threadIdx.y;   // 0..7
    #pragma unroll
    for (int r = 0; r < 32; r += 8)
        tile[r + ty][tx] = W[(size_t)(k0 + r + ty) * NDIM + n0 + tx];
    __syncthreads();
    #pragma unroll
    for (int r = 0; r < 32; r += 8)
        Wt[(size_t)(n0 + r + ty) * KDIM + k0 + tx] = (bf16)tile[tx][r + ty];
}

// ---------------------------------------------------------------------------
// bf16 MFMA GEMM: out[M][N] = A[M][K] * Bt[N][K]^T + bias  (m97 pattern)
// + granule-XOR LDS swizzle (round-8 win: kills 16-way b128 read conflicts).
// + XCD-aware block remap (round-10): XCD = linear_id % 8; give XCD k the
//   M-tiles == k (mod 8) for ALL N, with co-resident neighbors sharing one
//   N-tile. Per-XCD L2 hot set: A 8x0.26 MB + one B-tile < 4 MB (was: N-
//   fastest interleave -> ~800 MB cross-L2 A+B traffic, BW-bound).
//   Requires gridX*gridY % 64 == 0 and gridY == 64 M-tiles (both GEMMs ok).
// Columns n < oscale_n get (acc+bias)*oscale in f32 before the store.
// ---------------------------------------------------------------------------
template <int N, bool OUT_BF16>
__global__ __launch_bounds__(256) void gemm_bf16(const bf16* __restrict__ A,
                                                 const bf16* __restrict__ Bt,
                                                 const float* __restrict__ bias,
                                                 void* __restrict__ outp,
                                                 float oscale, int oscale_n) {
    constexpr int K = 1024;
    __shared__ __align__(16) bf16 As[128 * 64];
    __shared__ __align__(16) bf16 Bs[128 * 64];

    const int tid  = threadIdx.x;
    const int w    = tid >> 6;
    const int lane = tid & 63;
    const int wm   = w & 1, wn = w >> 1;
    const int quad = lane >> 4, c16 = lane & 15;

    // XCD-aware remap (bijective: lin <-> (x8, q&7, q>>3) <-> (mIdx, nIdx))
    const int lin = (int)(blockIdx.y * gridDim.x + blockIdx.x);
    const int x8  = lin & 7;
    const int q   = lin >> 3;
    const int m0  = (x8 + 8 * (q & 7)) * 128;
    const int n0  = (q >> 3) * 128;

    const int srow = lane >> 3;                      // 0..7
    const int scol = ((lane & 7) ^ srow) * 8;        // swizzled source granule
    const int sw   = c16 & 7;                        // fragment-read swizzle key

    f32x4 acc[4][4] = {};

    for (int kt = 0; kt < K / 64; ++kt) {
        const int kk = kt * 64;
        #pragma unroll
        for (int i = 0; i < 4; ++i) {
            const int arow = 32 * w + 8 * i;
            __builtin_amdgcn_global_load_lds(
                (const __attribute__((address_space(1))) void*)(A + (size_t)(m0 + arow + srow) * K + kk + scol),
                (__attribute__((address_space(3))) void*)(&As[arow * 64]),
                16, 0, 0);
            __builtin_amdgcn_global_load_lds(
                (const __attribute__((address_space(1))) void*)(Bt + (size_t)(n0 + arow + srow) * K + kk + scol),
                (__attribute__((address_space(3))) void*)(&Bs[arow * 64]),
                16, 0, 0);
        }
        __syncthreads();

        #pragma unroll
        for (int ks = 0; ks < 2; ++ks) {
            const int go = ((ks * 4 + quad) ^ sw) * 8;   // swizzled granule offset
            bf16x8 af[4], bfv[4];
            #pragma unroll
            for (int mb = 0; mb < 4; ++mb)
                af[mb] = *(const bf16x8*)&As[(wm * 64 + mb * 16 + c16) * 64 + go];
            #pragma unroll
            for (int nb = 0; nb < 4; ++nb)
                bfv[nb] = *(const bf16x8*)&Bs[(wn * 64 + nb * 16 + c16) * 64 + go];
            #pragma unroll
            for (int mb = 0; mb < 4; ++mb)
                #pragma unroll
                for (int nb = 0; nb < 4; ++nb)
                    acc[mb][nb] = MFMA16(af[mb], bfv[nb], acc[mb][nb]);
        }
        __syncthreads();
    }

    #pragma unroll
    for (int nb = 0; nb < 4; ++nb) {
        const int n = n0 + wn * 64 + nb * 16 + c16;
        const float bv = bias[n];
        const float sc = (n < oscale_n) ? oscale : 1.0f;
        #pragma unroll
        for (int mb = 0; mb < 4; ++mb) {
            const int mbase = m0 + wm * 64 + mb * 16 + quad * 4;
            #pragma unroll
            for (int r = 0; r < 4; ++r) {
                float v = (acc[mb][nb][r] + bv) * sc;
                if (OUT_BF16)
                    ((bf16*)outp)[(size_t)(mbase + r) * N + n] = (bf16)v;
                else
                    ((float*)outp)[(size_t)(mbase + r) * N + n] = v;
            }
        }
    }
}

// ---------------------------------------------------------------------------
// Flash-style causal attention, v7 (unchanged from round 9 for attribution):
// split-K flash-decoding, two-phase CU-uniform fold, 17 k-iters per block,
// S^T=K*Q^T register-resident P, unnormalized bf16 partials + f32 l.
// ---------------------------------------------------------------------------
__global__ __launch_bounds__(256, 2) void attn_fwd(const bf16* __restrict__ qkv,
                                                   bf16* __restrict__ yp0,
                                                   bf16* __restrict__ yp1,
                                                   float* __restrict__ lp) {
    __shared__ __align__(16) bf16 Ks2[2][4096];       // [buf][512*key8 + 64*dgrp + 8*k7 + d7]
    __shared__ __align__(16) bf16 Vs[2][64 * 72];     // [buf][d][key], stride 72
#if !HAVE_K16
    __shared__ __align__(16) bf16 Ps[4][32 * 72];     // fallback: [wave][q][key]
#endif

    const int x    = blockIdx.x;                      // 0..15
    const int xq   = x >> 1;                          // 0..7
    const int sgl  = x & 1;                           // key-range half
    const int h    = blockIdx.y;
    const int bb   = blockIdx.z;
    const int tid  = threadIdx.x;
    const int w    = tid >> 6;
    const int lane = tid & 63;
    const int quad = lane >> 4, c16 = lane & 15;

    const size_t base = (size_t)(bb * T) * QKV_LD;

    const int g = tid >> 5;   // 0..7  : d-group for V staging
    const int p = tid & 31;   // 0..31 : key-pair for V staging

    bf16* __restrict__ ydst = sgl ? yp1 : yp0;
    float* __restrict__ ldst = lp + (size_t)sgl * Mrows * Hn;

    for (int ph = 0; ph < 2; ++ph) {
        const int qt = ph ? xq : (15 - xq);           // phase 0: heavy tile
        const int q0 = qt * 128;
        const int rowbase = q0 + w * 32;
        const int start = sgl ? (qt + 1) : 0;         // first k-tile of my half
        const int nkt = qt + 1;                       // iterations in my half

        // protect LDS restage against stragglers of the previous phase
        __syncthreads();

        // ---- prologue: stage tile (start) into buffer 0 ----
        {
            const int kb = start * 64;
            #pragma unroll
            for (int ii = 0; ii < 2; ++ii) {
                const int i = 2 * w + ii;
                const bf16* gp = qkv + base + (size_t)(kb + 8 * i + (lane & 7)) * QKV_LD + Cd + h * 64 + (lane >> 3) * 8;
                __builtin_amdgcn_global_load_lds(
                    (const __attribute__((address_space(1))) void*)gp,
                    (__attribute__((address_space(3))) void*)(&Ks2[0][i * 512]), 16, 0, 0);
            }
            const bf16* vp = qkv + base + (size_t)(kb + 2 * p) * QKV_LD + 2 * Cd + h * 64 + g * 8;
            bf16x8 va = *(const bf16x8*)vp;
            bf16x8 vb = *(const bf16x8*)(vp + QKV_LD);
            #pragma unroll
            for (int j = 0; j < 8; ++j) {
                union { bf16 hh[2]; uint32_t u; } pk;
                pk.hh[0] = va[j]; pk.hh[1] = vb[j];
                *(uint32_t*)&Vs[0][(8 * g + j) * 72 + 2 * p] = pk.u;
            }
        }

        // Q fragments (pre-scaled): lane holds Q[q=c16][d=quad*8+j (+32 for ks=1)]
        bf16x8 qf[2][2];
        #pragma unroll
        for (int mb = 0; mb < 2; ++mb) {
            const bf16* qp = qkv + base + (size_t)(rowbase + 16 * mb + c16) * QKV_LD + h * 64 + quad * 8;
            qf[mb][0] = *(const bf16x8*)qp;
            qf[mb][1] = *(const bf16x8*)(qp + 32);
        }

        f32x4 yacc[2][4] = {};     // HAVE_K16: Y^T[d=quad*4+r][q=c16]
        float lsum[2] = {};

        for (int j = 0; j < nkt; ++j) {
            const int cur = j & 1, nxt = cur ^ 1;
            const int k0 = (start + j) * 64;
            __syncthreads();

            // prefetch tile start+j+1
            bf16x8 va, vb;
            const bool more = (j + 1 < nkt);
            if (more) {
                const int kn = k0 + 64;
                #pragma unroll
                for (int ii = 0; ii < 2; ++ii) {
                    const int i = 2 * w + ii;
                    const bf16* gp = qkv + base + (size_t)(kn + 8 * i + (lane & 7)) * QKV_LD + Cd + h * 64 + (lane >> 3) * 8;
                    __builtin_amdgcn_global_load_lds(
                        (const __attribute__((address_space(1))) void*)gp,
                        (__attribute__((address_space(3))) void*)(&Ks2[nxt][i * 512]), 16, 0, 0);
                }
                const bf16* vp = qkv + base + (size_t)(kn + 2 * p) * QKV_LD + 2 * Cd + h * 64 + g * 8;
                va = *(const bf16x8*)vp;
                vb = *(const bf16x8*)(vp + QKV_LD);
            }

            if (k0 <= rowbase + 31) {   // wave-uniform skip of fully-masked tiles
                // ---- S^T = K Q^T : lane holds S^T[key=16blk+4quad+r][q=c16] ----
                f32x4 s[2][4] = {};
                #pragma unroll
                for (int ks = 0; ks < 2; ++ks)
                    #pragma unroll
                    for (int blk = 0; blk < 4; ++blk) {
                        const bf16x8 kf = *(const bf16x8*)
                            &Ks2[cur][(2 * blk + (c16 >> 3)) * 512 + (4 * ks + quad) * 64 + (c16 & 7) * 8];
                        #pragma unroll
                        for (int mb = 0; mb < 2; ++mb)
                            s[mb][blk] = MFMA16(kf, qf[mb][ks], s[mb][blk]);
                    }

                // ---- softmax: mask + exp2 only (scale pre-folded into Q) ----
#if HAVE_K16
                union B4 { bf16x4 v; s16x4 s; } pb[2][4];
#endif
                #pragma unroll
                for (int mb = 0; mb < 2; ++mb) {
                    const int rb = rowbase + 16 * mb;
                    const int qglob = rb + c16;
                    const bool needMask = (k0 + 63 > rb);   // vs MIN q of block
                    #pragma unroll
                    for (int blk = 0; blk < 4; ++blk) {
                        #pragma unroll
                        for (int r = 0; r < 4; ++r) {
                            const int key = k0 + blk * 16 + quad * 4 + r;
                            float e = s[mb][blk][r];
                            if (needMask) e = (key > qglob) ? -INFINITY : e;
                            float pv = EXP2(e);
                            lsum[mb] += pv;
#if HAVE_K16
                            pb[mb][blk].v[r] = (bf16)pv;
#else
                            Ps[w][(mb * 16 + c16) * 72 + blk * 16 + quad * 4 + r] = (bf16)pv;
#endif
                        }
                    }
                }

#if HAVE_K16
                // ---- Y^T += V^T P^T from registers ----
                #pragma unroll
                for (int blk = 0; blk < 4; ++blk)
                    #pragma unroll
                    for (int d16 = 0; d16 < 4; ++d16) {
                        union B4u { bf16x4 v; s16x4 s; } vf;
                        vf.v = *(const bf16x4*)&Vs[cur][(d16 * 16 + c16) * 72 + blk * 16 + quad * 4];
                        #pragma unroll
                        for (int mb = 0; mb < 2; ++mb)
                            yacc[mb][d16] = __builtin_amdgcn_mfma_f32_16x16x16bf16_1k(
                                vf.s, pb[mb][blk].s, yacc[mb][d16], 0, 0, 0);
                    }
#else
                asm volatile("s_waitcnt lgkmcnt(0)" ::: "memory");
                #pragma unroll
                for (int ks = 0; ks < 2; ++ks) {
                    bf16x8 pf0 = *(const bf16x8*)&Ps[w][(0 * 16 + c16) * 72 + ks * 32 + quad * 8];
                    bf16x8 pf1 = *(const bf16x8*)&Ps[w][(1 * 16 + c16) * 72 + ks * 32 + quad * 8];
                    #pragma unroll
                    for (int d16 = 0; d16 < 4; ++d16) {
                        const bf16x8 vfr = *(const bf16x8*)&Vs[cur][(d16 * 16 + c16) * 72 + ks * 32 + quad * 8];
                        yacc[0][d16] = MFMA16(pf0, vfr, yacc[0][d16]);
                        yacc[1][d16] = MFMA16(pf1, vfr, yacc[1][d16]);
                    }
                }
#endif
            }

            // write prefetched V (transposed, packed u32 -> conflict-free)
            if (more) {
                #pragma unroll
                for (int j2 = 0; j2 < 8; ++j2) {
                    union { bf16 hh[2]; uint32_t u; } pk;
                    pk.hh[0] = va[j2]; pk.hh[1] = vb[j2];
                    *(uint32_t*)&Vs[nxt][(8 * g + j2) * 72 + 2 * p] = pk.u;
                }
            }
        }

        // ---- deferred l reduction over quads (lane bits 4,5) ----
        #pragma unroll
        for (int mb = 0; mb < 2; ++mb) {
            lsum[mb] += __shfl_xor(lsum[mb], 16);
            lsum[mb] += __shfl_xor(lsum[mb], 32);
        }

        // ---- epilogue: UNNORMALIZED partial + l ----
#if HAVE_K16
        #pragma unroll
        for (int mb = 0; mb < 2; ++mb) {
            const int row = rowbase + 16 * mb + c16;
            bf16* yw = ydst + (size_t)(bb * T + row) * Cd + h * 64;
            #pragma unroll
            for (int d16 = 0; d16 < 4; ++d16) {
                bf16x4 o;
                #pragma unroll
                for (int r = 0; r < 4; ++r)
                    o[r] = (bf16)(yacc[mb][d16][r]);
                *(bf16x4*)(yw + d16 * 16 + quad * 4) = o;
            }
            if (quad == 0)
                ldst[(size_t)(bb * T + row) * Hn + h] = lsum[mb];
        }
#else
        #pragma unroll
        for (int mb = 0; mb < 2; ++mb)
            #pragma unroll
            for (int r = 0; r < 4; ++r) {
                const float lsv = __shfl(lsum[mb], quad * 4 + r);
                const int row = rowbase + 16 * mb + quad * 4 + r;
                bf16* yw = ydst + (size_t)(bb * T + row) * Cd + h * 64;
                #pragma unroll
                for (int d16 = 0; d16 < 4; ++d16)
                    yw[d16 * 16 + c16] = (bf16)(yacc[mb][d16][r]);
                if (c16 == 0)
                    ldst[(size_t)(bb * T + row) * Hn + h] = lsv;
            }
#endif
    }
}

// ---------------------------------------------------------------------------
// Combine split-K partials: y = (y0 + y1) / (l0 + l1). 8 elems/thread,
// all 8 within one head (64 % 8 == 0). In-place safe (y aliases yp0).
// ---------------------------------------------------------------------------
__global__ __launch_bounds__(256) void attn_combine(const bf16* __restrict__ yp0,
                                                    const bf16* __restrict__ yp1,
                                                    const float* __restrict__ lp,
                                                    bf16* __restrict__ y) {
    int i = (blockIdx.x * 256 + threadIdx.x) * 8;
    int row = i >> 10;          // / Cd
    int hh  = (i & 1023) >> 6;  // head
    float l = lp[(size_t)row * Hn + hh] + lp[(size_t)Mrows * Hn + (size_t)row * Hn + hh];
    float inv = 1.f / l;
    bf16x8 a = *(const bf16x8*)(yp0 + i);
    bf16x8 b = *(const bf16x8*)(yp1 + i);
    bf16x8 o;
    #pragma unroll
    for (int j = 0; j < 8; ++j)
        o[j] = (bf16)(((float)a[j] + (float)b[j]) * inv);
    *(bf16x8*)(y + i) = o;
}

// ---------------------------------------------------------------------------
extern "C" void kernel_launch(void* const* d_in, const int* in_sizes, int n_in,
                              void* d_out, int out_size, void* d_ws, size_t ws_size,
                              hipStream_t stream) {
    const float* x      = (const float*)d_in[0];
    const float* W_attn = (const float*)d_in[1];
    const float* b_attn = (const float*)d_in[2];
    const float* W_proj = (const float*)d_in[3];
    const float* b_proj = (const float*)d_in[4];
    float* out = (float*)d_out;

    bf16* xb   = (bf16*)d_ws;                               // 16.8 MB
    bf16* Wat  = xb  + (size_t)Mrows * Cd;                  // 6.3 MB
    bf16* Wpt  = Wat + (size_t)QKV_LD * Cd;                 // 2.1 MB
    bf16* qkv  = Wpt + (size_t)Cd * Cd;                     // 50.3 MB
    bf16* yb   = qkv + (size_t)Mrows * QKV_LD;              // 16.8 MB (yp0 + combined)
    bf16* yp1  = yb  + (size_t)Mrows * Cd;                  // 16.8 MB
    float* lp  = (float*)(yp1 + (size_t)Mrows * Cd);        // 1.05 MB (2 x M x H)

    cvt_f32_bf16<<<(Mrows * Cd) / (256 * 8), 256, 0, stream>>>(x, xb, Mrows * Cd);
    transpose_cvt<Cd, QKV_LD><<<dim3(QKV_LD / 32, Cd / 32), dim3(32, 8), 0, stream>>>(W_attn, Wat);
    transpose_cvt<Cd, Cd><<<dim3(Cd / 32, Cd / 32), dim3(32, 8), 0, stream>>>(W_proj, Wpt);

    // Q columns (n < 1024) pre-scaled by 1/sqrt(D)*log2e for the attn exp2
    gemm_bf16<QKV_LD, true><<<dim3(QKV_LD / 128, Mrows / 128), 256, 0, stream>>>(
        xb, Wat, b_attn, qkv, QSCALE, Cd);

    attn_fwd<<<dim3(16, Hn, Bsz), 256, 0, stream>>>(qkv, yb, yp1, lp);
    attn_combine<<<(Mrows * Cd) / (256 * 8), 256, 0, stream>>>(yb, yp1, lp, yb);

    gemm_bf16<Cd, false><<<dim3(Cd / 128, Mrows / 128), 256, 0, stream>>>(
        yb, Wpt, b_proj, out, 1.0f, 0);
}